// Round 1
// baseline (760.127 us; speedup 1.0000x reference)
//
#include <hip/hip_runtime.h>
#include <stdint.h>

// Conductance-LIF network, persistent event-driven kernel. Round 7.
//
// r6 measured 2.53 us/step with VALUBusy 13%, HBM 4% => pure latency convoy:
// cross-XCD LLC publish->poll round trips + serial dependent row-gather loads.
// This round:
//   * XCD co-location: blockIdx = j*32 + b  =>  all 8 column-slice blocks of
//     batch b land on XCD b%8 under the %8 round-robin dispatch heuristic.
//     Spike words then cross blocks through the XCD-SHARED L2.
//   * Dual-path exchange: producers publish each word TWICE — relaxed
//     agent-scope atomic into recpub (LLC; the r6-proven, placement-
//     independent, deadlock-free protocol) AND a plain sc0 store into a
//     SEPARATE recfast array (write-through into the local L2). Consumers
//     alternate sc0 polls (L2 hit ~100-200cyc when co-located) with
//     agent-scope polls (always-correct fallback). recfast corruption in
//     adversarial placements can only yield stale tags (8B entries never
//     tear; byte-masked writebacks), which the tag check filters; recpub is
//     atomics-only so its LLC values stay pristine. A kernel-entry agent
//     acquire fence drops stale cross-dispatch L2 lines (ws is re-poisoned
//     0xAAAAAAAA between runs; tags 1..256 never collide with poison).
//     Correctness NEVER depends on block->XCD placement (perf heuristic only).
//   * Latency-pipelined gathers: rec rows of all ready words drained through
//     a 4-deep batched loop (4 independent float4 loads in flight; compiler
//     emits counted vmcnt) instead of one dependent load per row. Cost
//     accepted: per-XCD L2 no longer holds a private W slice; spiking rows
//     stream from LLC with 8-consumer reuse in L2.
//   * FF off the critical path: the FF gather for step t+1 (mask = ballot of
//     the prefetched I[t+1]) runs AFTER the barrier, overlapping the 9
//     non-tail waves with the tail's reduce/LIF/publish.
// Sync stays fence-free in-loop: flag+data in ONE 64-bit word (hi32 = t+1,
// lo32 = 32 spike bits), relaxed agent atomics only. All 256 blocks are
// co-resident and the publish for step t precedes any wait on step-t words
// (induction over t) -> no deadlock, unchanged from r6.

__device__ __forceinline__ uint64_t ld_g_sc0(const uint64_t* p) {
    uint64_t v;
    asm volatile("global_load_dwordx2 %0, %1, off sc0\n\t"
                 "s_waitcnt vmcnt(0)"
                 : "=v"(v) : "v"(p) : "memory");
    return v;
}

__device__ __forceinline__ void st_g_sc0(uint64_t* p, uint64_t v) {
    asm volatile("global_store_dwordx2 %0, %1, off sc0"
                 :: "v"(p), "v"(v) : "memory");
}

// batched-4 latency-pipelined FF row gather (rows from a 64-bit spike mask)
__device__ __forceinline__ float4 ff_gather(const float* __restrict__ WF,
                                            uint64_t mm, uint32_t rowbase,
                                            uint32_t colbase) {
    float4 acc = make_float4(0.f, 0.f, 0.f, 0.f);
    while (mm) {
        uint32_t q0 = 0, q1 = 0, q2 = 0, q3 = 0;
        bool e1 = false, e2 = false, e3 = false;
        { int bq = (int)__builtin_ctzll(mm); mm &= mm - 1; q0 = rowbase + (uint32_t)bq; }
        if (mm) { int bq = (int)__builtin_ctzll(mm); mm &= mm - 1; q1 = rowbase + (uint32_t)bq; e1 = true; }
        if (mm) { int bq = (int)__builtin_ctzll(mm); mm &= mm - 1; q2 = rowbase + (uint32_t)bq; e2 = true; }
        if (mm) { int bq = (int)__builtin_ctzll(mm); mm &= mm - 1; q3 = rowbase + (uint32_t)bq; e3 = true; }
        float4 u0, u1, u2, u3;
        u0 = *(const float4*)(WF + q0 * 1536u + colbase);
        if (e1) u1 = *(const float4*)(WF + q1 * 1536u + colbase);
        if (e2) u2 = *(const float4*)(WF + q2 * 1536u + colbase);
        if (e3) u3 = *(const float4*)(WF + q3 * 1536u + colbase);
        acc.x += u0.x; acc.y += u0.y; acc.z += u0.z; acc.w += u0.w;
        if (e1) { acc.x += u1.x; acc.y += u1.y; acc.z += u1.z; acc.w += u1.w; }
        if (e2) { acc.x += u2.x; acc.y += u2.y; acc.z += u2.z; acc.w += u2.w; }
        if (e3) { acc.x += u3.x; acc.y += u3.y; acc.z += u3.z; acc.w += u3.w; }
    }
    return acc;
}

// pop lowest pending recurrent row across the wave's 4 word-masks
#define POP_ROW(RV, CV, HV)                                                        \
    {                                                                              \
        HV = false;                                                                \
        if (nb0)      { int _b = (int)__builtin_ctz(nb0); nb0 &= nb0 - 1;          \
                        RV = wbase + (uint32_t)_b;        CV = (cm0 >> _b) & 1u; HV = true; } \
        else if (nb1) { int _b = (int)__builtin_ctz(nb1); nb1 &= nb1 - 1;          \
                        RV = wbase + 32u + (uint32_t)_b;  CV = (cm1 >> _b) & 1u; HV = true; } \
        else if (nb2) { int _b = (int)__builtin_ctz(nb2); nb2 &= nb2 - 1;          \
                        RV = wbase + 64u + (uint32_t)_b;  CV = (cm2 >> _b) & 1u; HV = true; } \
        else if (nb3) { int _b = (int)__builtin_ctz(nb3); nb3 &= nb3 - 1;          \
                        RV = wbase + 96u + (uint32_t)_b;  CV = (cm3 >> _b) & 1u; HV = true; } \
    }

__global__ __launch_bounds__(768) void snn_lif_kernel(
    const float* __restrict__ I,     // [32][256][768] input spikes (0/1)
    const float* __restrict__ W,     // [1536][1536] recurrent weights (row = pre)
    const float* __restrict__ WF,    // [768][1536]  FF weights (row = input)
    const float* __restrict__ sf,    // [2][2] scaling (pre ct, post ct)
    const float* __restrict__ sfF,   // [1][2] FF scaling (post ct)
    const int*   __restrict__ ct,    // [1536] cell type 0/1
    float* __restrict__ out,         // spk [32][256][1536] then volt [...]
    uint64_t* __restrict__ recpub,   // [32][256][48]: (tag<<32)|bits — atomics only
    uint64_t* __restrict__ recfast)  // same layout, sc0 fast copy (may be null)
{
    // drop stale clean L2 lines from a previous dispatch (recfast aliasing)
    __builtin_amdgcn_fence(__ATOMIC_ACQUIRE, "agent");

    const int tid = threadIdx.x;
    const int b   = blockIdx.x & 31;   // batch: its 8 slice-blocks share one
    const int j   = blockIdx.x >> 5;   // XCD under %8 round-robin (perf only)
    const int wv  = tid >> 6;          // wave 0..11
    const int wl  = tid & 63;          // lane
    const bool havefast = (recfast != nullptr);

    __shared__ float4   part0[2][12][48];   // rec ct0 partials (dbuf)
    __shared__ float4   part1[2][12][48];   // rec ct1 partials
    __shared__ float4   partF[2][12][48];   // FF partials
    __shared__ uint32_t ctm32_sh[48];       // cell-type bits per 32-neuron word

    // ---- cell-type bitmask via block-wide ballots (2 x 768) ----
    for (int r = 0; r < 2; ++r) {
        int c = ct[r * 768 + tid];
        uint64_t bal = __ballot(c != 0);
        if (wl == 0) {
            ctm32_sh[r * 24 + wv * 2]     = (uint32_t)bal;
            ctm32_sh[r * 24 + wv * 2 + 1] = (uint32_t)(bal >> 32);
        }
    }
    __syncthreads();

    // hoist this wave's 4 word ct-masks to registers (block constants)
    const uint32_t cm0 = ctm32_sh[wv * 4 + 0];
    const uint32_t cm1 = ctm32_sh[wv * 4 + 1];
    const uint32_t cm2 = ctm32_sh[wv * 4 + 2];
    const uint32_t cm3 = ctm32_sh[wv * 4 + 3];

    // ---- owner-neuron constants (threads 0..191 own neuron m) ----
    const int m = j * 192 + ((tid < 192) ? tid : 0);
    const int   myct = ct[m];
    const float s0m  = sf[myct];
    const float s1m  = sf[2 + myct];
    const float sFm  = sfF[myct];
    const float lc   = (myct == 0) ? (1.0f / 200.0f) : (1.0f / 100.0f);
    const float refsteps = (myct == 0) ? 2.0f : 1.0f;
    const float ar0 = expf(-1.0f / 0.5f),  ad0 = expf(-1.0f / 2.0f);
    const float ar1 = expf(-1.0f / 2.0f),  ad1 = expf(-1.0f / 100.0f);
    const float ar2 = expf(-1.0f / 0.5f),  ad2 = expf(-1.0f / 5.0f);
    const float arF = expf(-1.0f / 0.5f),  adF = expf(-1.0f / 2.0f);

    float U = -65.0f, refc = 0.0f;
    float x0 = 0, g0 = 0, x1 = 0, g1 = 0, x2 = 0, g2 = 0, xF = 0, gF = 0;

    const int  btbase  = b * 256;
    const bool gl      = (wl < 48);                         // gather lane
    // clamp so all 64 lanes compute valid addresses (lanes 48..63 duplicate
    // lane 47's 16B segment: zero extra cache lines, lets gather loads run
    // unguarded); LDS partial writes stay gl-guarded.
    const uint32_t colbase = (uint32_t)(j * 192) + (uint32_t)((wl < 48 ? wl : 47) * 4);
    const uint32_t wbase   = (uint32_t)(wv * 128);          // this wave's first rec row
    const uint32_t ffbase  = (uint32_t)(wv * 64);           // this wave's first FF row

    // pre-loop: FF accumulator for t=0 (mask = own ballot of I[b,0,:])
    float4 aF;
    {
        float iv = __builtin_nontemporal_load(
            &I[(uint32_t)btbase * 768u + (uint32_t)tid]);
        uint64_t f0 = __ballot(iv > 0.5f);
        aF = ff_gather(WF, f0, ffbase, colbase);
    }

    for (int t = 0; t < 256; ++t) {
        float4 a0 = make_float4(0.f, 0.f, 0.f, 0.f);
        float4 a1 = a0;

        // ---- poll 4 rec words; drain arrivals through a 4-deep pipeline ----
        if (t > 0) {
            uint32_t ready = 0;
            const uint32_t pbase = (uint32_t)(btbase + t - 1) * 48u + (uint32_t)(wv * 4);
            uint32_t nb0 = 0, nb1 = 0, nb2 = 0, nb3 = 0;
            int it = 0;
            do {
                uint64_t pv = 0;
                if (wl < 4) {
                    if (havefast && ((it & 1) == 0))
                        pv = ld_g_sc0(&recfast[pbase + (uint32_t)wl]);       // L2 fast path
                    else
                        pv = __hip_atomic_load(&recpub[pbase + (uint32_t)wl],
                                               __ATOMIC_RELAXED, __HIP_MEMORY_SCOPE_AGENT);
                }
                ++it;
                const uint32_t plo = (uint32_t)pv;
                const uint32_t phi = (uint32_t)(pv >> 32);
                if (!(ready & 1u) && (uint32_t)__builtin_amdgcn_readlane(phi, 0) == (uint32_t)t) {
                    ready |= 1u; nb0 = (uint32_t)__builtin_amdgcn_readlane(plo, 0);
                }
                if (!(ready & 2u) && (uint32_t)__builtin_amdgcn_readlane(phi, 1) == (uint32_t)t) {
                    ready |= 2u; nb1 = (uint32_t)__builtin_amdgcn_readlane(plo, 1);
                }
                if (!(ready & 4u) && (uint32_t)__builtin_amdgcn_readlane(phi, 2) == (uint32_t)t) {
                    ready |= 4u; nb2 = (uint32_t)__builtin_amdgcn_readlane(plo, 2);
                }
                if (!(ready & 8u) && (uint32_t)__builtin_amdgcn_readlane(phi, 3) == (uint32_t)t) {
                    ready |= 8u; nb3 = (uint32_t)__builtin_amdgcn_readlane(plo, 3);
                }
                // merged drain: up to 4 independent row loads in flight
                while (nb0 | nb1 | nb2 | nb3) {
                    uint32_t r0 = 0, r1 = 0, r2 = 0, r3 = 0;
                    uint32_t c0 = 0, c1 = 0, c2 = 0, c3 = 0;
                    bool h0 = false, h1 = false, h2 = false, h3 = false;
                    POP_ROW(r0, c0, h0); POP_ROW(r1, c1, h1);
                    POP_ROW(r2, c2, h2); POP_ROW(r3, c3, h3);
                    float4 w0, w1, w2, w3;
                    w0 = *(const float4*)(W + r0 * 1536u + colbase);
                    if (h1) w1 = *(const float4*)(W + r1 * 1536u + colbase);
                    if (h2) w2 = *(const float4*)(W + r2 * 1536u + colbase);
                    if (h3) w3 = *(const float4*)(W + r3 * 1536u + colbase);
                    if (c0) { a1.x += w0.x; a1.y += w0.y; a1.z += w0.z; a1.w += w0.w; }
                    else    { a0.x += w0.x; a0.y += w0.y; a0.z += w0.z; a0.w += w0.w; }
                    if (h1) {
                        if (c1) { a1.x += w1.x; a1.y += w1.y; a1.z += w1.z; a1.w += w1.w; }
                        else    { a0.x += w1.x; a0.y += w1.y; a0.z += w1.z; a0.w += w1.w; }
                    }
                    if (h2) {
                        if (c2) { a1.x += w2.x; a1.y += w2.y; a1.z += w2.z; a1.w += w2.w; }
                        else    { a0.x += w2.x; a0.y += w2.y; a0.z += w2.z; a0.w += w2.w; }
                    }
                    if (h3) {
                        if (c3) { a1.x += w3.x; a1.y += w3.y; a1.z += w3.z; a1.w += w3.w; }
                        else    { a0.x += w3.x; a0.y += w3.y; a0.z += w3.z; a0.w += w3.w; }
                    }
                }
            } while (ready != 0xFu);
        }

        // prefetch next-step input AFTER the polls (poll's vmcnt(0) must not
        // collide with it); consumed by the ballot after the barrier
        float ivn = 0.0f;
        if (t < 255)
            ivn = __builtin_nontemporal_load(
                &I[(uint32_t)(btbase + t + 1) * 768u + (uint32_t)tid]);

        const int buf = t & 1;
        if (gl) {
            part0[buf][wv][wl] = a0;
            part1[buf][wv][wl] = a1;
            partF[buf][wv][wl] = aF;   // FF of step t, gathered last iteration
        }
        __syncthreads();                // partials of ALL waves visible

        // ---- tail (threads 0..191): reduce, LIF, publish FIRST, store ----
        if (tid < 192) {
            const float* p0 = (const float*)&part0[buf][0][0];
            const float* p1 = (const float*)&part1[buf][0][0];
            const float* pF = (const float*)&partF[buf][0][0];
            float z0s = 0.f, z1s = 0.f, zFs = 0.f;
            #pragma unroll
            for (int k = 0; k < 12; ++k) {
                z0s += p0[k * 192 + tid];
                z1s += p1[k * 192 + tid];
                zFs += pF[k * 192 + tid];
            }
            z0s *= s0m; z1s *= s1m; zFs *= sFm;
            x0 = ar0 * x0 + z0s;  g0 = ad0 * g0 + x0;   // syn0 (pre ct0)
            x1 = ar1 * x1 + z0s;  g1 = ad1 * g1 + x1;   // syn1 (pre ct0, same z0)
            x2 = ar2 * x2 + z1s;  g2 = ad2 * g2 + x2;   // syn2 (pre ct1)
            xF = arF * xF + zFs;  gF = adF * gF + xF;   // feed-forward
            const float gtot = g0 + 0.5f * g1 + g2 + gF;   // gbar=[1,.5,1], FF 1
            const float gE   = -70.0f * g2;                // gbar*Erev=[0,0,-70], FF 0
            const float Isyn = gE - gtot * U;
            float Un = U + lc * (10.0f * (-65.0f - U) + Isyn);
            if (refc > 0.0f) Un = -65.0f;
            refc = fmaxf(refc - 1.0f, 0.0f);
            const bool s = (Un - (-50.0f)) >= 0.0f;
            // publish ASAP: slow (agent/LLC, always correct) then fast (sc0/L2)
            const uint64_t bal = __ballot(s);
            if (wl == 0 || wl == 32) {
                const uint32_t half = (wl == 0) ? (uint32_t)bal : (uint32_t)(bal >> 32);
                const uint32_t word = (uint32_t)(j * 6 + wv * 2) + (wl == 32 ? 1u : 0u);
                const uint32_t widx = (uint32_t)(btbase + t) * 48u + word;
                const uint64_t v = ((uint64_t)(uint32_t)(t + 1) << 32) | half;
                __hip_atomic_store(&recpub[widx], v, __ATOMIC_RELAXED,
                                   __HIP_MEMORY_SCOPE_AGENT);
                if (havefast) st_g_sc0(&recfast[widx], v);
            }
            const float Uo = s ? -65.0f : Un;
            refc = s ? refsteps : refc;
            U = Uo;
            const uint32_t oidx = (uint32_t)(btbase + t) * 1536u + (uint32_t)m;
            __builtin_nontemporal_store(s ? 1.0f : 0.0f, &out[oidx]);
            __builtin_nontemporal_store(Uo, &out[12582912u + oidx]);
        }

        // ---- FF for step t+1, off the rec critical path: waves 3..11 run it
        // while waves 0..2 are in the tail ----
        {
            uint64_t fmask = __ballot(ivn > 0.5f);
            aF = ff_gather(WF, fmask, ffbase, colbase);
        }
        // no second barrier: partials double-buffered; no wave can reach step
        // t+2's writes before all waves passed step t+1's barrier.
    }
}

extern "C" void kernel_launch(void* const* d_in, const int* in_sizes, int n_in,
                              void* d_out, int out_size, void* d_ws, size_t ws_size,
                              hipStream_t stream) {
    const float* I   = (const float*)d_in[0];   // input_spikes (32,256,768)
    const float* W   = (const float*)d_in[1];   // weights (1536,1536)
    const float* WF  = (const float*)d_in[2];   // weights_FF (768,1536)
    const float* sf  = (const float*)d_in[3];   // scaling_factors (2,2)
    const float* sfF = (const float*)d_in[4];   // scaling_factors_FF (1,2)
    const int*   ct  = (const int*)d_in[5];     // cell_type_indices (1536)
    // d_in[6] cell_type_indices_FF: all zeros, folded into sfF indexing.

    const size_t SZ = 32ull * 256ull * 48ull * 8ull;      // 3,145,728 B
    uint64_t* recpub  = (uint64_t*)d_ws;                  // atomic/LLC array
    uint64_t* recfast = (ws_size >= 2 * SZ)               // sc0/L2 fast array
                        ? (uint64_t*)((char*)d_ws + SZ) : nullptr;

    snn_lif_kernel<<<dim3(256), dim3(768), 0, stream>>>(
        I, W, WF, sf, sfF, ct, (float*)d_out, recpub, recfast);
}